// Round 3
// baseline (1446.690 us; speedup 1.0000x reference)
//
#include <hip/hip_runtime.h>
#include <math.h>

// ---- problem constants ----
#define HW 65536
#define WP 129
#define NPOS 33024          // 256*129
#define MMAX 16257          // max m value + 1 (127*128+1)
#define PI_F 3.14159265358979f

__device__ __forceinline__ int rev7(int x){ return (int)(__brev((unsigned)x) >> 25); }
__device__ __forceinline__ int rev8(int x){ return (int)(__brev((unsigned)x) >> 24); }

// ---------------- permutation maps (counting sort over m = mu(i)*j) --------------
__global__ void k_hist(int* __restrict__ hist) {
  int v = blockIdx.x*256 + threadIdx.x;
  if (v >= MMAX) return;
  int cnt;
  if (v == 0) cnt = 512;  // row0(129) + j=0 rows 1..254 (254) + row255(129)
  else {
    cnt = 0;
    for (int d = 1; d <= 127; ++d)
      if (v % d == 0 && v / d <= 128) cnt += 2;   // rows i=d and i=255-d
  }
  hist[v] = cnt;
}

__global__ void k_scan(const int* __restrict__ hist, int* __restrict__ base) {
  __shared__ int part[512];
  int t = threadIdx.x;
  int lo = t*32, hi = lo+32; if (hi > MMAX) hi = MMAX;
  int s = 0;
  if (lo < MMAX) for (int i = lo; i < hi; ++i) s += hist[i];
  part[t] = s;
  __syncthreads();
  for (int off = 1; off < 512; off <<= 1) {
    int v = (t >= off) ? part[t-off] : 0;
    __syncthreads();
    part[t] += v;
    __syncthreads();
  }
  int acc = part[t] - s;  // exclusive
  if (lo < MMAX) for (int i = lo; i < hi; ++i) { base[i] = acc; acc += hist[i]; }
}

__global__ void k_build(const int* __restrict__ base, int* __restrict__ idx, int* __restrict__ inv) {
  int v = blockIdx.x*256 + threadIdx.x;
  if (v >= MMAX) return;
  int s = base[v];
  if (v == 0) {
    for (int j = 0; j < 129; ++j) { idx[s] = j; inv[j] = s; ++s; }
    for (int i = 1; i < 255; ++i) { int p = i*129; idx[s] = p; inv[p] = s; ++s; }
    for (int j = 0; j < 129; ++j) { int p = 255*129 + j; idx[s] = p; inv[p] = s; ++s; }
  } else {
    for (int i = 1; i < 255; ++i) {
      int d = (i < 128) ? i : 255 - i;
      if (v % d == 0) {
        int j = v / d;
        if (j <= 128) { int p = i*129 + j; idx[s] = p; inv[p] = s; ++s; }
      }
    }
  }
}

// t-space: t = k*256 + h  (transposed natural layout)
__global__ void k_maps(const int* __restrict__ idx, const int* __restrict__ inv,
                       int* __restrict__ partner_t, int* __restrict__ half_t) {
  int t = blockIdx.x*256 + threadIdx.x;
  if (t >= NPOS) return;
  int k = t >> 8, h = t & 255;
  int p = h*129 + k;
  int s = inv[p];
  int f = (s >= 16512) ? 1 : 0;
  int s2 = f ? (s - 16512) : (s + 16512);
  int pp = idx[s2];
  int kk = pp % 129, hh = pp / 129;
  partner_t[t] = kk*256 + hh;
  half_t[t] = f;
}

__global__ void k_zero(float* __restrict__ g) {
  int i = blockIdx.x*256 + threadIdx.x;
  if (i < 34816) g[i] = 0.f;   // gram(32768) + nq(1024) + nk(1024)
}

// ---------------- 64->64 pointwise conv, 2 pixels/thread -------------------------
__global__ __launch_bounds__(256) void k_conv64(const float* __restrict__ in,
        const float* __restrict__ w, float* __restrict__ outp) {
  __shared__ float ws[4096];
  for (int i = threadIdx.x; i < 4096; i += 256) ws[i] = w[i];
  __syncthreads();
  int lb = blockIdx.y;
  int p0 = (blockIdx.x*256 + threadIdx.x)*2;
  const float* xb = in + ((size_t)lb*64)*HW + p0;
  float xv[128];
  #pragma unroll
  for (int c = 0; c < 64; ++c) {
    float2 t = *(const float2*)(xb + (size_t)c*HW);
    xv[2*c] = t.x; xv[2*c+1] = t.y;
  }
  float* ob = outp + ((size_t)lb*64)*HW + p0;
  for (int o = 0; o < 64; ++o) {
    float a0 = 0.f, a1 = 0.f;
    #pragma unroll
    for (int c = 0; c < 64; c += 4) {
      float4 wv = *(const float4*)(&ws[o*64 + c]);
      a0 += wv.x*xv[2*c+0]; a1 += wv.x*xv[2*c+1];
      a0 += wv.y*xv[2*c+2]; a1 += wv.y*xv[2*c+3];
      a0 += wv.z*xv[2*c+4]; a1 += wv.z*xv[2*c+5];
      a0 += wv.w*xv[2*c+6]; a1 += wv.w*xv[2*c+7];
    }
    *(float2*)(ob + (size_t)o*HW) = make_float2(a0, a1);
  }
}

// ------- fused depthwise3x3 + row rfft (256 real -> 129 cplx), t-layout store ----
__global__ __launch_bounds__(512) void k_dwrowfft(const float* __restrict__ tmp,
        const float* __restrict__ wdw, float* __restrict__ planes,
        int tensor, size_t psz) {
  __shared__ float rows[10][260];
  __shared__ float2 Z[8][128];
  __shared__ float2 X[8][132];
  int wave = threadIdx.x >> 6, lane = threadIdx.x & 63;
  int lb = blockIdx.z, c = blockIdx.y;
  int h0 = blockIdx.x * 8;
  const float* ib = tmp + ((size_t)lb*64 + c)*HW;
  for (int e = threadIdx.x; e < 2560; e += 512) {
    int r = e >> 8, col = e & 255;
    int y = h0 - 1 + r;
    rows[r][col] = (y >= 0 && y < 256) ? ib[y*256 + col] : 0.f;
  }
  const float* w9 = wdw + ((size_t)tensor*64 + c)*9;
  float w0=w9[0],w1=w9[1],w2=w9[2],w3=w9[3],w4=w9[4],w5=w9[5],w6=w9[6],w7=w9[7],w8=w9[8];
  __syncthreads();
  float d[4];
  #pragma unroll
  for (int q = 0; q < 4; ++q) {
    int col = (q < 2) ? (2*lane + q) : (128 + 2*lane + (q-2));
    float acc = rows[wave+0][col]*w1 + rows[wave+1][col]*w4 + rows[wave+2][col]*w7;
    if (col > 0)   acc += rows[wave+0][col-1]*w0 + rows[wave+1][col-1]*w3 + rows[wave+2][col-1]*w6;
    if (col < 255) acc += rows[wave+0][col+1]*w2 + rows[wave+1][col+1]*w5 + rows[wave+2][col+1]*w8;
    d[q] = acc;
  }
  Z[wave][rev7(lane)]    = make_float2(d[0], d[1]);
  Z[wave][rev7(lane+64)] = make_float2(d[2], d[3]);
  __syncthreads();
  for (int L = 1; L <= 64; L <<= 1) {
    int kk = lane & (L-1);
    int i0 = ((lane ^ kk) << 1) | kk;
    float sn, cs; sincosf(-PI_F * kk / L, &sn, &cs);
    float2 u = Z[wave][i0], t = Z[wave][i0+L];
    float tr = t.x*cs - t.y*sn;
    float ti = t.x*sn + t.y*cs;
    Z[wave][i0]   = make_float2(u.x+tr, u.y+ti);
    Z[wave][i0+L] = make_float2(u.x-tr, u.y-ti);
    __syncthreads();
  }
  for (int kk = lane; kk <= 128; kk += 64) {
    float2 Zk = Z[wave][kk & 127];
    float2 Zm = Z[wave][(128-kk) & 127];
    float Er = 0.5f*(Zk.x + Zm.x), Ei = 0.5f*(Zk.y - Zm.y);
    float Or = 0.5f*(Zk.y + Zm.y), Oi = 0.5f*(Zm.x - Zk.x);
    float sn, cs; sincosf(-PI_F * kk / 128.0f, &sn, &cs);
    float Xr = Er + cs*Or - sn*Oi;
    float Xi = Ei + cs*Oi + sn*Or;
    X[wave][kk] = make_float2(Xr*(1.0f/256.0f), Xi*(1.0f/256.0f));
  }
  __syncthreads();
  float* pre = planes + (size_t)(tensor*2)*psz + ((size_t)lb*64 + c)*NPOS;
  float* pim = pre + psz;
  for (int e = threadIdx.x; e < 1032; e += 512) {
    int k = e >> 3, hh = e & 7;
    float2 v = X[hh][k];
    pre[(size_t)k*256 + h0 + hh] = v.x;
    pim[(size_t)k*256 + h0 + hh] = v.y;
  }
}

// ---------------- column FFT: 256-pt complex, in-place on planes -----------------
__global__ __launch_bounds__(512) void k_colfft(float* __restrict__ planes,
        int tensor, size_t psz) {
  __shared__ float2 Z[8][258];
  int wave = threadIdx.x >> 6, lane = threadIdx.x & 63;
  int lb = blockIdx.z, c = blockIdx.y;
  int kreal = blockIdx.x*8 + wave;
  int k = (kreal < 129) ? kreal : 128;
  float* pre = planes + (size_t)(tensor*2)*psz + ((size_t)lb*64 + c)*NPOS + (size_t)k*256;
  float* pim = pre + psz;
  #pragma unroll
  for (int i = 0; i < 4; ++i) {
    int h = lane + 64*i;
    Z[wave][rev8(h)] = make_float2(pre[h], pim[h]);
  }
  __syncthreads();   // all reads done before any same-block write (k=128 dup waves)
  for (int L = 1; L <= 128; L <<= 1) {
    #pragma unroll
    for (int jj = 0; jj < 2; ++jj) {
      int j = lane + 64*jj;
      int kk = j & (L-1);
      int i0 = ((j ^ kk) << 1) | kk;
      float sn, cs; sincosf(-PI_F * kk / L, &sn, &cs);
      float2 u = Z[wave][i0], t = Z[wave][i0+L];
      float tr = t.x*cs - t.y*sn;
      float ti = t.x*sn + t.y*cs;
      Z[wave][i0]   = make_float2(u.x+tr, u.y+ti);
      Z[wave][i0+L] = make_float2(u.x-tr, u.y-ti);
    }
    __syncthreads();
  }
  if (kreal <= 128) {
    #pragma unroll
    for (int i = 0; i < 4; ++i) {
      float2 v = Z[wave][lane + 64*i];
      pre[lane+64*i] = v.x;
      pim[lane+64*i] = v.y;
    }
  }
}

// ---------------- Gram + row norms (per b,head), half/partner trick --------------
__global__ __launch_bounds__(256) void k_gram(const float* __restrict__ planes,
    const int* __restrict__ partner_t, const int* __restrict__ half_t,
    float* __restrict__ gram, float* __restrict__ nq, float* __restrict__ nk,
    int b0, size_t psz) {
  __shared__ float qa[16][65], ka[16][65], kb[16][65];
  __shared__ int ptn[64];
  __shared__ int hf[64];
  int lb = blockIdx.y >> 3, h = blockIdx.y & 7;
  int bh = (b0 + lb)*8 + h;
  const float* qp = planes + (size_t)(h>=4 ? 1:0)*psz + ((size_t)(lb*64 + (h&3)*16))*NPOS;
  const float* kp = planes + (size_t)(2 + (h>=4 ? 1:0))*psz + ((size_t)(lb*64 + (h&3)*16))*NPOS;
  int tc = threadIdx.x & 15, td = threadIdx.x >> 4;
  float a00=0.f,a01=0.f,a10=0.f,a11=0.f, q0=0.f,q1=0.f,k0a=0.f,k1a=0.f;
  for (int it = 0; it < 6; ++it) {
    int t0 = (blockIdx.x*6 + it)*64;
    if (threadIdx.x < 64) {
      ptn[threadIdx.x] = partner_t[t0 + threadIdx.x];
      hf[threadIdx.x]  = half_t[t0 + threadIdx.x];
    }
    __syncthreads();
    for (int e = threadIdx.x; e < 1024; e += 256) {
      int cc = e >> 6, j = e & 63;
      qa[cc][j] = qp[(size_t)cc*NPOS + t0 + j];
      ka[cc][j] = kp[(size_t)cc*NPOS + t0 + j];
      kb[cc][j] = kp[(size_t)cc*NPOS + ptn[j]];
    }
    __syncthreads();
    #pragma unroll 4
    for (int j = 0; j < 64; ++j) {
      float q = qa[tc][j], v1 = ka[td][j], v2 = kb[td][j];
      int f = hf[j];
      float p1 = q*v1, p2 = q*v2;
      if (f) { a11 += p1; a10 += p2; } else { a00 += p1; a01 += p2; }
      if (td == 0) { float qq = q*q; if (f) q1 += qq; else q0 += qq; }
      if (tc == 0) { float kk = v1*v1; if (f) k1a += kk; else k0a += kk; }
    }
    __syncthreads();
  }
  float* G = gram + (size_t)bh*1024;
  atomicAdd(&G[(2*tc+0)*32 + 2*td+0], a00);
  atomicAdd(&G[(2*tc+0)*32 + 2*td+1], a01);
  atomicAdd(&G[(2*tc+1)*32 + 2*td+0], a10);
  atomicAdd(&G[(2*tc+1)*32 + 2*td+1], a11);
  if (td == 0) { atomicAdd(&nq[bh*32 + 2*tc], q0); atomicAdd(&nq[bh*32 + 2*tc+1], q1); }
  if (tc == 0) { atomicAdd(&nk[bh*32 + 2*td], k0a); atomicAdd(&nk[bh*32 + 2*td+1], k1a); }
}

// ---------------- softmax1 with cosine normalization + temperature ---------------
__global__ void k_attn(const float* __restrict__ gram, const float* __restrict__ nq,
                       const float* __restrict__ nk, const float* __restrict__ temp,
                       float* __restrict__ attn, int b0) {
  __shared__ float lnk[32];
  int bh = b0*8 + blockIdx.x, h = bh & 7;
  int r = threadIdx.x;
  if (r < 32) lnk[r] = fmaxf(sqrtf(nk[bh*32 + r]), 1e-12f);
  __syncthreads();
  if (r >= 32) return;
  float T = temp[h];
  float nqr = fmaxf(sqrtf(nq[bh*32 + r]), 1e-12f);
  float e[32]; float s = 0.f;
  #pragma unroll
  for (int c = 0; c < 32; ++c) {
    float g = gram[(size_t)bh*1024 + r*32 + c] / (nqr * lnk[c]) * T;
    e[c] = expf(g);
    s += e[c];
  }
  float is = 1.0f / (s + 1.0f);
  #pragma unroll
  for (int c = 0; c < 32; ++c) attn[(size_t)bh*1024 + r*32 + c] = e[c] * is;
}

// ---------------- O = attn @ V, written in natural t-layout ----------------------
// O aliases planes 0,1 (Q planes, dead after k_gram); V = planes 4,5.
__global__ __launch_bounds__(256) void k_o(const float* __restrict__ planes,
    const float* __restrict__ attn, const int* __restrict__ partner_t,
    const int* __restrict__ half_t, float* __restrict__ O, int b0, size_t psz) {
  __shared__ float At[8][1024];
  int lb = blockIdx.y;
  for (int e = threadIdx.x; e < 8192; e += 256)
    At[e>>10][e&1023] = attn[((size_t)(b0+lb)*8)*1024 + e];
  __syncthreads();
  int t = blockIdx.x*256 + threadIdx.x;
  int f = half_t[t], pt = partner_t[t];
  #pragma unroll 1
  for (int hh = 0; hh < 8; ++hh) {
    const float* vp = planes + (size_t)(4 + (hh>=4 ? 1:0))*psz + ((size_t)(lb*64 + (hh&3)*16))*NPOS;
    float* op = O + (size_t)(hh>=4 ? 1:0)*psz + ((size_t)(lb*64 + (hh&3)*16))*NPOS;
    float w0[16], w1[16];
    #pragma unroll
    for (int d = 0; d < 16; ++d) {
      float va = vp[(size_t)d*NPOS + t];
      float vb = vp[(size_t)d*NPOS + pt];
      w0[d] = f ? vb : va;
      w1[d] = f ? va : vb;
    }
    #pragma unroll
    for (int c = 0; c < 16; ++c) {
      const float4* Ar = (const float4*)&At[hh][(2*c+f)*32];
      float acc = 0.f;
      #pragma unroll
      for (int d = 0; d < 8; ++d) {
        float4 a4 = Ar[d];
        acc += a4.x*w0[2*d] + a4.y*w1[2*d] + a4.z*w0[2*d+1] + a4.w*w1[2*d+1];
      }
      op[(size_t)c*NPOS + t] = acc;
    }
  }
}

// ---------------- inverse column FFT (e^{+}), transpose store, 1/256 -------------
// reads O (planes 0,1 space), writes IT (planes 2,3 space) — disjoint.
__global__ __launch_bounds__(512) void k_colifft(const float* __restrict__ O,
        float2* __restrict__ IT, size_t psz) {
  __shared__ float2 Z[8][258];
  int wave = threadIdx.x >> 6, lane = threadIdx.x & 63;
  int lb = blockIdx.z, c = blockIdx.y;
  int kreal = blockIdx.x*8 + wave;
  int k = (kreal < 129) ? kreal : 128;
  const float* pre = O + ((size_t)lb*64 + c)*NPOS + (size_t)k*256;
  const float* pim = pre + psz;
  #pragma unroll
  for (int i = 0; i < 4; ++i) {
    int h = lane + 64*i;
    Z[wave][rev8(h)] = make_float2(pre[h], pim[h]);
  }
  __syncthreads();
  for (int L = 1; L <= 128; L <<= 1) {
    #pragma unroll
    for (int jj = 0; jj < 2; ++jj) {
      int j = lane + 64*jj;
      int kk = j & (L-1);
      int i0 = ((j ^ kk) << 1) | kk;
      float sn, cs; sincosf(PI_F * kk / L, &sn, &cs);
      float2 u = Z[wave][i0], t = Z[wave][i0+L];
      float tr = t.x*cs - t.y*sn;
      float ti = t.x*sn + t.y*cs;
      Z[wave][i0]   = make_float2(u.x+tr, u.y+ti);
      Z[wave][i0+L] = make_float2(u.x-tr, u.y-ti);
    }
    __syncthreads();
  }
  float2* outp = IT + ((size_t)lb*64 + c)*256*WP;
  int k0 = blockIdx.x*8;
  for (int e = threadIdx.x; e < 2048; e += 512) {
    int hpos = e >> 3, kk2 = e & 7;
    if (k0 + kk2 <= 128) {
      float2 v = Z[kk2][hpos];
      outp[(size_t)hpos*WP + k0 + kk2] = make_float2(v.x*(1.0f/256.0f), v.y*(1.0f/256.0f));
    }
  }
}

// ---------------- row irfft: 129 complex -> 256 real ----------------------------
// reads IT (planes 2,3 space), writes sp (planes 4,5 space) — disjoint.
__global__ __launch_bounds__(512) void k_rowirfft(const float2* __restrict__ IT,
        float* __restrict__ sp) {
  __shared__ float2 Xl[8][132];
  __shared__ float2 Z[8][128];
  int wave = threadIdx.x >> 6, lane = threadIdx.x & 63;
  int lb = blockIdx.z, c = blockIdx.y;
  int h = blockIdx.x*8 + wave;
  const float2* row = IT + (((size_t)lb*64 + c)*256 + h)*WP;
  float2 v0 = row[lane];     if (lane == 0) v0.y = 0.f;       // imag of DC dropped
  float2 v1 = row[lane+64];
  Xl[wave][lane] = v0;
  Xl[wave][lane+64] = v1;
  if (lane == 0) { float2 vn = row[128]; vn.y = 0.f; Xl[wave][128] = vn; } // Nyquist
  __syncthreads();
  for (int u = 0; u < 2; ++u) {
    int kk = lane + 64*u;
    float2 Xk = Xl[wave][kk];
    float2 Xm = Xl[wave][128-kk];
    float Ar = Xk.x + Xm.x, Ai = Xk.y - Xm.y;   // X[k]+conj(X[128-k])
    float Br = Xk.x - Xm.x, Bi = Xk.y + Xm.y;   // X[k]-conj(X[128-k])
    float sn, cs; sincosf(PI_F * kk / 128.0f, &sn, &cs);
    float tr = cs*Br - sn*Bi, ti = cs*Bi + sn*Br;  // e^{+2pi i k/256} * B
    Z[wave][rev7(kk)] = make_float2(Ar - ti, Ai + tr);
  }
  __syncthreads();
  for (int L = 1; L <= 64; L <<= 1) {
    int kk = lane & (L-1);
    int i0 = ((lane ^ kk) << 1) | kk;
    float sn, cs; sincosf(PI_F * kk / L, &sn, &cs);
    float2 u2 = Z[wave][i0], t = Z[wave][i0+L];
    float tr = t.x*cs - t.y*sn;
    float ti = t.x*sn + t.y*cs;
    Z[wave][i0]   = make_float2(u2.x+tr, u2.y+ti);
    Z[wave][i0+L] = make_float2(u2.x-tr, u2.y-ti);
    __syncthreads();
  }
  float2* orow = (float2*)(sp + (((size_t)lb*64 + c)*256 + h)*256);
  orow[lane]    = Z[wave][lane];
  orow[lane+64] = Z[wave][lane+64];
}

// =================================================================================
extern "C" void kernel_launch(void* const* d_in, const int* in_sizes, int n_in,
                              void* d_out, int out_size, void* d_ws, size_t ws_size,
                              hipStream_t stream) {
  const float* x      = (const float*)d_in[0];
  const float* w_qkv  = (const float*)d_in[1];
  const float* w_dw   = (const float*)d_in[2];
  const float* w_proj = (const float*)d_in[3];
  const float* temp   = (const float*)d_in[4];
  float* out = (float*)d_out;

  char* ws = (char*)d_ws;
  int*   hist = (int*)(ws + 0);
  int*   base = (int*)(ws + 65536);
  int*   idx  = (int*)(ws + 131072);
  int*   inv  = (int*)(ws + 263168);
  int*   ptn  = (int*)(ws + 395264);
  int*   hlf  = (int*)(ws + 527360);
  float* gram = (float*)(ws + 659456);
  float* nq   = (float*)(ws + 790528);
  float* nk   = (float*)(ws + 794624);
  float* attn = (float*)(ws + 798720);

  // footprint = SMALL + NB * 6 planes; tmp/O/IT/sp all alias d_out or dead planes
  const size_t SMALL   = 1048576;
  const size_t PLANESB = 50724864;   // 6 * 64 * 33024 * 4 bytes per batch elem
  int NB = 1;
  if (ws_size >= SMALL + 2*PLANESB) NB = 2;
  if (ws_size >= SMALL + 4*PLANESB) NB = 4;

  float*  P   = (float*)(ws + SMALL);
  size_t  psz = (size_t)NB * 64 * NPOS;   // one plane, in floats
  float*  O   = P;                        // aliases planes 0,1 (Q, dead after gram)
  float2* IT  = (float2*)(P + 2*psz);     // aliases planes 2,3 (K, dead after gram)
  float*  sp  = P + 4*psz;                // aliases planes 4,5 (V, dead after k_o)

  // permutation maps (recomputed every call; ws is re-poisoned by harness)
  k_hist <<<dim3(64), dim3(256), 0, stream>>>(hist);
  k_scan <<<dim3(1),  dim3(512), 0, stream>>>(hist, base);
  k_build<<<dim3(64), dim3(256), 0, stream>>>(base, idx, inv);
  k_maps <<<dim3(129),dim3(256), 0, stream>>>(idx, inv, ptn, hlf);
  k_zero <<<dim3(136),dim3(256), 0, stream>>>(gram);

  for (int b0 = 0; b0 < 4; b0 += NB) {
    float* tmpb = out + (size_t)b0*64*HW;   // d_out as staging; slot dead until final conv
    // forward: per-tensor conv1x1 -> fused dwconv+rowfft -> in-place colfft
    for (int tn = 0; tn < 3; ++tn) {
      k_conv64  <<<dim3(128, NB), dim3(256), 0, stream>>>(
          x + (size_t)b0*64*HW, w_qkv + (size_t)tn*64*64, tmpb);
      k_dwrowfft<<<dim3(32, 64, NB), dim3(512), 0, stream>>>(tmpb, w_dw, P, tn, psz);
      k_colfft  <<<dim3(17, 64, NB), dim3(512), 0, stream>>>(P, tn, psz);
    }
    // attention
    k_gram<<<dim3(86, NB*8), dim3(256), 0, stream>>>(P, ptn, hlf, gram, nq, nk, b0, psz);
    k_attn<<<dim3(NB*8), dim3(64), 0, stream>>>(gram, nq, nk, temp, attn, b0);
    k_o   <<<dim3(129, NB), dim3(256), 0, stream>>>(P, attn, ptn, hlf, O, b0, psz);
    // inverse
    k_colifft <<<dim3(17, 64, NB), dim3(512), 0, stream>>>(O, IT, psz);
    k_rowirfft<<<dim3(32, 64, NB), dim3(512), 0, stream>>>(IT, sp);
    k_conv64  <<<dim3(128, NB), dim3(256), 0, stream>>>(sp, w_proj, out + (size_t)b0*64*HW);
  }
}